// Round 3
// baseline (952.218 us; speedup 1.0000x reference)
//
#include <hip/hip_runtime.h>
#include <math.h>

#define NN 100000
#define NE 1600000
#define NG 1000
#define BN_EPS 1e-5f
#define SCAN_BLK 256
#define NSCAN ((NN + SCAN_BLK - 1) / SCAN_BLK)   // 391
#define AGG_BLOCKS 2048
#define CAP 512      // per-wave LDS index cache (ints)
#define RNG 500      // nodes per bucket (200*500 == 100000 exactly)
#define NBUK 200
#define SLOTS 16     // staged pairs per bucket (128B flush)
#define BIN_BLOCKS 256

typedef unsigned short ushort_t;

__device__ inline float bf2f(ushort_t u) {
    union { unsigned int i; float f; } c; c.i = ((unsigned int)u) << 16; return c.f;
}
__device__ inline ushort_t f2bf(float f) {
    union { float f; unsigned int i; } c; c.f = f;
    unsigned int u = c.i;
    u += 0x7FFFu + ((u >> 16) & 1u);   // RNE
    return (ushort_t)(u >> 16);
}

// ---------------- init ----------------

__global__ __launch_bounds__(256) void k_init(float* pooled, float* stats, int* bcnt) {
    int i = blockIdx.x * blockDim.x + threadIdx.x;
    int stride = gridDim.x * blockDim.x;
    for (int j = i; j < 5 * NG * 64; j += stride) pooled[j] = 0.f;
    for (int j = i; j < 1024; j += stride) stats[j] = 0.f;
    for (int j = i; j < NBUK; j += stride) bcnt[j] = 0;
}

__global__ __launch_bounds__(256) void k_f2bf(const float* __restrict__ x, ushort_t* __restrict__ o) {
    int i = blockIdx.x * blockDim.x + threadIdx.x;
    int stride = gridDim.x * blockDim.x;
    for (int j = i; j < NN * 64; j += stride) o[j] = f2bf(x[j]);
}

// ---------------- edge binning (radix partition by dst/RNG) ----------------

__global__ __launch_bounds__(256) void k_bin_count(const int* __restrict__ dst, int* __restrict__ bcnt) {
    __shared__ int l[NBUK];
    for (int t = threadIdx.x; t < NBUK; t += 256) l[t] = 0;
    __syncthreads();
    int i = blockIdx.x * blockDim.x + threadIdx.x;
    int stride = gridDim.x * blockDim.x;
    for (int e = i; e < NE; e += stride) atomicAdd(&l[dst[e] / RNG], 1);
    __syncthreads();
    for (int t = threadIdx.x; t < NBUK; t += 256) if (l[t]) atomicAdd(&bcnt[t], l[t]);
}

__global__ __launch_bounds__(256) void k_bucket_scan(const int* __restrict__ bcnt,
                                                     int* __restrict__ boff, int* __restrict__ bcur) {
    __shared__ int s[256];
    int t = threadIdx.x;
    int v = (t < NBUK) ? bcnt[t] : 0;
    s[t] = v;
    __syncthreads();
    for (int o = 1; o < 256; o <<= 1) {
        int x = (t >= o) ? s[t - o] : 0;
        __syncthreads();
        s[t] += x;
        __syncthreads();
    }
    if (t < NBUK) { boff[t] = s[t] - v; bcur[t] = s[t] - v; }
    if (t == 0) boff[NBUK] = NE;
}

__global__ __launch_bounds__(256) void k_bin(
    const int* __restrict__ src, const int* __restrict__ dst,
    int* __restrict__ bcur, uint2* __restrict__ binned)
{
    __shared__ int occ[NBUK];
    __shared__ uint2 sbuf[NBUK][SLOTS];
    int tid = threadIdx.x;
    for (int t = tid; t < NBUK; t += 256) occ[t] = 0;
    __syncthreads();
    int per = (NE + gridDim.x - 1) / gridDim.x;
    int start = blockIdx.x * per, end = min(NE, start + per);
    for (int base = start; base < end; base += 256) {
        int e = base + tid;
        if (e < end) {
            unsigned s = (unsigned)src[e], d = (unsigned)dst[e];
            int b = (int)(d / RNG);
            int slot = atomicAdd(&occ[b], 1);
            if (slot < SLOTS) sbuf[b][slot] = make_uint2(s, d);
            else {
                int p = atomicAdd(&bcur[b], 1);
                binned[p] = make_uint2(s, d);
            }
        }
        __syncthreads();
        for (int b = tid; b < NBUK; b += 256) {
            if (occ[b] >= SLOTS) {
                int p = atomicAdd(&bcur[b], SLOTS);
#pragma unroll
                for (int k = 0; k < SLOTS; k++) binned[p + k] = sbuf[b][k];
                occ[b] = 0;
            }
        }
        __syncthreads();
    }
    for (int b = tid; b < NBUK; b += 256) {
        int c = min(occ[b], SLOTS);
        if (c > 0) {
            int p = atomicAdd(&bcur[b], c);
            for (int k = 0; k < c; k++) binned[p + k] = sbuf[b][k];
        }
    }
}

// per-bucket node histogram (replaces global-atomic k_hist)
__global__ __launch_bounds__(256) void k_nodecnt(
    const uint2* __restrict__ binned, const int* __restrict__ boff,
    int* __restrict__ cnt)
{
    __shared__ int lcnt[RNG];
    int b = blockIdx.x;
    int base = b * RNG;
    for (int t = threadIdx.x; t < RNG; t += 256) lcnt[t] = 0;
    __syncthreads();
    int e0 = boff[b], e1 = boff[b + 1];
    for (int e = e0 + threadIdx.x; e < e1; e += 256)
        atomicAdd(&lcnt[binned[e].y - base], 1);
    __syncthreads();
    for (int t = threadIdx.x; t < RNG; t += 256) cnt[base + t] = lcnt[t];
}

// ---------------- node-level scan ----------------

__global__ __launch_bounds__(SCAN_BLK) void k_scanA(const int* __restrict__ cnt,
                                                    int* __restrict__ off,
                                                    int* __restrict__ bsum) {
    __shared__ int s[SCAN_BLK];
    int t = threadIdx.x;
    int i = blockIdx.x * SCAN_BLK + t;
    int v = (i < NN) ? cnt[i] : 0;
    s[t] = v;
    __syncthreads();
    for (int o = 1; o < SCAN_BLK; o <<= 1) {
        int x = (t >= o) ? s[t - o] : 0;
        __syncthreads();
        s[t] += x;
        __syncthreads();
    }
    if (i < NN) off[i] = s[t] - v;
    if (t == SCAN_BLK - 1) bsum[blockIdx.x] = s[t];
}

__global__ __launch_bounds__(512) void k_scanB(int* __restrict__ bsum) {
    __shared__ int s[512];
    int t = threadIdx.x;
    int v = (t < NSCAN) ? bsum[t] : 0;
    s[t] = v;
    __syncthreads();
    for (int o = 1; o < 512; o <<= 1) {
        int x = (t >= o) ? s[t - o] : 0;
        __syncthreads();
        s[t] += x;
        __syncthreads();
    }
    if (t < NSCAN) bsum[t] = s[t] - v;
}

__global__ __launch_bounds__(256) void k_scanC(int* __restrict__ off, const int* __restrict__ bsum,
                                               int* __restrict__ cur) {
    int i = blockIdx.x * blockDim.x + threadIdx.x;
    int stride = gridDim.x * blockDim.x;
    for (int j = i; j < NN; j += stride) {
        int o = off[j] + bsum[j / SCAN_BLK];
        off[j] = o;
        cur[j] = o;
    }
    if (i == 0) off[NN] = NE;
}

// per-bucket scatter: all csr writes land in one ~32KB window per workgroup
__global__ __launch_bounds__(256) void k_scatter2(
    const uint2* __restrict__ binned, const int* __restrict__ boff,
    int* __restrict__ cur, int* __restrict__ csr)
{
    int b = blockIdx.x;
    int e0 = boff[b], e1 = boff[b + 1];
    for (int e = e0 + threadIdx.x; e < e1; e += 256) {
        uint2 p = binned[e];
        int pos = atomicAdd(&cur[p.y], 1);
        csr[pos] = (int)p.x;
    }
}

// ---------------- fused layer kernels ----------------

__global__ __launch_bounds__(256) void k_agg_g1(
    const float* __restrict__ h, const ushort_t* __restrict__ hb,
    const int* __restrict__ csr, const int* __restrict__ off,
    const float* __restrict__ W1, float* __restrict__ y,
    float* __restrict__ stats1,
    const int* __restrict__ gid, float* __restrict__ pool0)
{
    __shared__ __align__(16) float buf[4][64];
    __shared__ int sidx[4][CAP];
    __shared__ float sred[128];
    int lane = threadIdx.x & 63;
    int wslot = threadIdx.x >> 6;
    int wid = blockIdx.x * 4 + wslot;
    int nw = AGG_BLOCKS * 4;
    int chunk = (NN + nw - 1) / nw;
    int n0 = wid * chunk, n1 = min(NN, n0 + chunk);

    float Wc[64];
#pragma unroll
    for (int k = 0; k < 64; k++) Wc[k] = W1[k * 64 + lane];

    float ls = 0.f, lss = 0.f;

    if (n0 < n1) {
        int e0 = off[n0];
        int eEnd = off[n1];
        int tot = eEnd - e0;
        int lim = min(tot, CAP);
        for (int t = lane; t < lim; t += 64) sidx[wslot][t] = csr[e0 + t];

        int curg = -1;
        float pacc = 0.f;

        for (int n = n0; n < n1; ++n) {
            float acc = h[(size_t)n * 64 + lane];
            if (pool0) {
                int g = gid[n];
                if (g != curg) {
                    if (curg >= 0) atomicAdd(&pool0[curg * 64 + lane], pacc);
                    curg = g; pacc = 0.f;
                }
                pacc += acc;
            }
            int s0 = off[n] - e0, s1 = off[n + 1] - e0;
            float a1 = 0.f, a2 = 0.f, a3 = 0.f;
            int j = s0;
            if (s1 <= lim) {
                for (; j + 4 <= s1; j += 4) {
                    int i0 = sidx[wslot][j],     i1 = sidx[wslot][j + 1],
                        i2 = sidx[wslot][j + 2], i3 = sidx[wslot][j + 3];
                    float v0 = bf2f(hb[(size_t)i0 * 64 + lane]);
                    float v1 = bf2f(hb[(size_t)i1 * 64 + lane]);
                    float v2 = bf2f(hb[(size_t)i2 * 64 + lane]);
                    float v3 = bf2f(hb[(size_t)i3 * 64 + lane]);
                    acc += v0; a1 += v1; a2 += v2; a3 += v3;
                }
                for (; j < s1; ++j) acc += bf2f(hb[(size_t)sidx[wslot][j] * 64 + lane]);
            } else {
                for (; j + 4 <= s1; j += 4) {
                    int i0 = csr[e0 + j],     i1 = csr[e0 + j + 1],
                        i2 = csr[e0 + j + 2], i3 = csr[e0 + j + 3];
                    float v0 = bf2f(hb[(size_t)i0 * 64 + lane]);
                    float v1 = bf2f(hb[(size_t)i1 * 64 + lane]);
                    float v2 = bf2f(hb[(size_t)i2 * 64 + lane]);
                    float v3 = bf2f(hb[(size_t)i3 * 64 + lane]);
                    acc += v0; a1 += v1; a2 += v2; a3 += v3;
                }
                for (; j < s1; ++j) acc += bf2f(hb[(size_t)csr[e0 + j] * 64 + lane]);
            }
            acc += (a1 + a2) + a3;

            buf[wslot][lane] = acc;
            float yl = 0.f;
#pragma unroll
            for (int k = 0; k < 16; k++) {
                float4 z4 = *(const float4*)&buf[wslot][k * 4];
                yl = fmaf(z4.x, Wc[4 * k], yl);
                yl = fmaf(z4.y, Wc[4 * k + 1], yl);
                yl = fmaf(z4.z, Wc[4 * k + 2], yl);
                yl = fmaf(z4.w, Wc[4 * k + 3], yl);
            }
            y[(size_t)n * 64 + lane] = yl;
            ls += yl;
            lss += yl * yl;
        }
        if (pool0 && curg >= 0) atomicAdd(&pool0[curg * 64 + lane], pacc);
    }

    if (threadIdx.x < 128) sred[threadIdx.x] = 0.f;
    __syncthreads();
    atomicAdd(&sred[lane], ls);
    atomicAdd(&sred[64 + lane], lss);
    __syncthreads();
    if (threadIdx.x < 128) atomicAdd(&stats1[threadIdx.x], sred[threadIdx.x]);
}

__global__ __launch_bounds__(256) void k_g2(
    const float* __restrict__ y, const float* __restrict__ stats1,
    const float* __restrict__ g1, const float* __restrict__ b1,
    const float* __restrict__ W2, float* __restrict__ z,
    float* __restrict__ stats2)
{
    __shared__ __align__(16) float buf[4][4][64];
    __shared__ float sred[128];
    int lane = threadIdx.x & 63;
    int wslot = threadIdx.x >> 6;
    int wid = blockIdx.x * 4 + wslot;
    int nw = AGG_BLOCKS * 4;
    int chunk = (NN + nw - 1) / nw;
    int n0 = wid * chunk, n1 = min(NN, n0 + chunk);

    float mean = stats1[lane] * (1.f / NN);
    float var  = stats1[64 + lane] * (1.f / NN) - mean * mean;
    float sc = rsqrtf(var + BN_EPS) * g1[lane];
    float sh = b1[lane] - mean * sc;

    float Wc[64];
#pragma unroll
    for (int k = 0; k < 64; k++) Wc[k] = W2[k * 64 + lane];

    float ls = 0.f, lss = 0.f;
    if (n0 < n1) {
        int n = n0;
        for (; n + 4 <= n1; n += 4) {
            float v0 = fmaxf(fmaf(y[(size_t)n * 64 + lane], sc, sh), 0.f);
            float v1 = fmaxf(fmaf(y[(size_t)(n + 1) * 64 + lane], sc, sh), 0.f);
            float v2 = fmaxf(fmaf(y[(size_t)(n + 2) * 64 + lane], sc, sh), 0.f);
            float v3 = fmaxf(fmaf(y[(size_t)(n + 3) * 64 + lane], sc, sh), 0.f);
            buf[wslot][0][lane] = v0;
            buf[wslot][1][lane] = v1;
            buf[wslot][2][lane] = v2;
            buf[wslot][3][lane] = v3;
#pragma unroll
            for (int r = 0; r < 4; ++r) {
                float zl = 0.f;
#pragma unroll
                for (int k = 0; k < 16; k++) {
                    float4 t4 = *(const float4*)&buf[wslot][r][k * 4];
                    zl = fmaf(t4.x, Wc[4 * k], zl);
                    zl = fmaf(t4.y, Wc[4 * k + 1], zl);
                    zl = fmaf(t4.z, Wc[4 * k + 2], zl);
                    zl = fmaf(t4.w, Wc[4 * k + 3], zl);
                }
                z[(size_t)(n + r) * 64 + lane] = zl;
                ls += zl;
                lss += zl * zl;
            }
        }
        for (; n < n1; ++n) {
            float v = fmaxf(fmaf(y[(size_t)n * 64 + lane], sc, sh), 0.f);
            buf[wslot][0][lane] = v;
            float zl = 0.f;
#pragma unroll
            for (int k = 0; k < 16; k++) {
                float4 t4 = *(const float4*)&buf[wslot][0][k * 4];
                zl = fmaf(t4.x, Wc[4 * k], zl);
                zl = fmaf(t4.y, Wc[4 * k + 1], zl);
                zl = fmaf(t4.z, Wc[4 * k + 2], zl);
                zl = fmaf(t4.w, Wc[4 * k + 3], zl);
            }
            z[(size_t)n * 64 + lane] = zl;
            ls += zl;
            lss += zl * zl;
        }
    }

    if (threadIdx.x < 128) sred[threadIdx.x] = 0.f;
    __syncthreads();
    atomicAdd(&sred[lane], ls);
    atomicAdd(&sred[64 + lane], lss);
    __syncthreads();
    if (threadIdx.x < 128) atomicAdd(&stats2[threadIdx.x], sred[threadIdx.x]);
}

__global__ __launch_bounds__(256) void k_a2(
    float* __restrict__ z,
    ushort_t* __restrict__ hb,      // bf16 mirror for next layer's gather
    const float* __restrict__ stats2,
    const float* __restrict__ g2, const float* __restrict__ b2,
    const int* __restrict__ gid, float* __restrict__ pool)
{
    int lane = threadIdx.x & 63;
    int wslot = threadIdx.x >> 6;
    int wid = blockIdx.x * 4 + wslot;
    int nw = AGG_BLOCKS * 4;
    int chunk = (NN + nw - 1) / nw;
    int n0 = wid * chunk, n1 = min(NN, n0 + chunk);
    if (n0 >= n1) return;

    float mean = stats2[lane] * (1.f / NN);
    float var  = stats2[64 + lane] * (1.f / NN) - mean * mean;
    float sc = rsqrtf(var + BN_EPS) * g2[lane];
    float sh = b2[lane] - mean * sc;

    int curg = -1;
    float pacc = 0.f;
    int n = n0;
    for (; n + 4 <= n1; n += 4) {
        float z0 = z[(size_t)n * 64 + lane];
        float z1 = z[(size_t)(n + 1) * 64 + lane];
        float z2v = z[(size_t)(n + 2) * 64 + lane];
        float z3 = z[(size_t)(n + 3) * 64 + lane];
        int g0 = gid[n], g1v = gid[n + 1], g2v = gid[n + 2], g3 = gid[n + 3];
        float vv[4] = {z0, z1, z2v, z3};
        int gg[4] = {g0, g1v, g2v, g3};
#pragma unroll
        for (int r = 0; r < 4; ++r) {
            float v = fmaxf(fmaf(vv[r], sc, sh), 0.f);
            z[(size_t)(n + r) * 64 + lane] = v;
            hb[(size_t)(n + r) * 64 + lane] = f2bf(v);
            if (gg[r] != curg) {
                if (curg >= 0) atomicAdd(&pool[curg * 64 + lane], pacc);
                curg = gg[r]; pacc = 0.f;
            }
            pacc += v;
        }
    }
    for (; n < n1; ++n) {
        float v = fmaxf(fmaf(z[(size_t)n * 64 + lane], sc, sh), 0.f);
        z[(size_t)n * 64 + lane] = v;
        hb[(size_t)n * 64 + lane] = f2bf(v);
        int g = gid[n];
        if (g != curg) {
            if (curg >= 0) atomicAdd(&pool[curg * 64 + lane], pacc);
            curg = g; pacc = 0.f;
        }
        pacc += v;
    }
    if (curg >= 0) atomicAdd(&pool[curg * 64 + lane], pacc);
}

// ---------------- epilogue ----------------

__global__ __launch_bounds__(256) void k_final(
    const float* __restrict__ pooled, const float* __restrict__ pW,
    const float* __restrict__ pb, float* __restrict__ out)
{
    int t = blockIdx.x * blockDim.x + threadIdx.x;
    int g = t >> 4;
    int c = t & 15;
    if (g >= NG) return;
    float acc = 0.f;
#pragma unroll
    for (int i = 0; i < 5; i++) {
        const float* P = pooled + (size_t)i * NG * 64 + g * 64;
        const float* W = pW + i * 64 * 16;
        float a = 0.f;
#pragma unroll
        for (int k = 0; k < 64; k++) a += P[k] * W[k * 16 + c];
        acc += a + pb[i * 16 + c];
    }
    float m = acc;
    for (int o = 1; o < 16; o <<= 1) m = fmaxf(m, __shfl_xor(m, o, 16));
    float e = expf(acc - m);
    float s = e;
    for (int o = 1; o < 16; o <<= 1) s += __shfl_xor(s, o, 16);
    out[g * 16 + c] = acc - m - logf(s);
}

// ---------------- launch ----------------

extern "C" void kernel_launch(void* const* d_in, const int* in_sizes, int n_in,
                              void* d_out, int out_size, void* d_ws, size_t ws_size,
                              hipStream_t stream) {
    const float* feat = (const float*)d_in[0];
    const float* W1   = (const float*)d_in[1];
    const float* W2   = (const float*)d_in[2];
    const float* bn1g = (const float*)d_in[3];
    const float* bn1b = (const float*)d_in[4];
    const float* bn2g = (const float*)d_in[5];
    const float* bn2b = (const float*)d_in[6];
    const float* pW   = (const float*)d_in[7];
    const float* pb   = (const float*)d_in[8];
    const int* src = (const int*)d_in[9];
    const int* dst = (const int*)d_in[10];
    const int* gid = (const int*)d_in[11];
    float* out = (float*)d_out;

    char* ws = (char*)d_ws;
    size_t o = 0;
    auto alloc = [&](size_t bytes) {
        void* p = ws + o;
        o += (bytes + 255) & ~(size_t)255;
        return p;
    };
    float* hbuf   = (float*)alloc((size_t)NN * 64 * 4);
    float* ybuf   = (float*)alloc((size_t)NN * 64 * 4);
    ushort_t* hbf = (ushort_t*)alloc((size_t)NN * 64 * 2);
    float* pooled = (float*)alloc((size_t)5 * NG * 64 * 4);
    float* stats  = (float*)alloc(1024 * 4);
    int* cnt  = (int*)alloc((size_t)NN * 4);
    int* off  = (int*)alloc((size_t)(NN + 1) * 4);
    int* cur  = (int*)alloc((size_t)NN * 4);
    int* csr  = (int*)alloc((size_t)NE * 4);
    uint2* binned = (uint2*)alloc((size_t)NE * 8);
    int* bcnt = (int*)alloc(NBUK * 4);
    int* boff = (int*)alloc((NBUK + 1) * 4);
    int* bcur = (int*)alloc(NBUK * 4);
    int* bsum = (int*)alloc(512 * 4);

    k_init<<<256, 256, 0, stream>>>(pooled, stats, bcnt);
    k_f2bf<<<2048, 256, 0, stream>>>(feat, hbf);
    k_bin_count<<<BIN_BLOCKS, 256, 0, stream>>>(dst, bcnt);
    k_bucket_scan<<<1, 256, 0, stream>>>(bcnt, boff, bcur);
    k_bin<<<BIN_BLOCKS, 256, 0, stream>>>(src, dst, bcur, binned);
    k_nodecnt<<<NBUK, 256, 0, stream>>>(binned, boff, cnt);
    k_scanA<<<NSCAN, SCAN_BLK, 0, stream>>>(cnt, off, bsum);
    k_scanB<<<1, 512, 0, stream>>>(bsum);
    k_scanC<<<512, 256, 0, stream>>>(off, bsum, cur);
    k_scatter2<<<NBUK, 256, 0, stream>>>(binned, boff, cur, csr);

    const float* hin = feat;
    for (int L = 0; L < 4; ++L) {
        float* s1 = stats + L * 256;
        float* s2 = s1 + 128;
        k_agg_g1<<<AGG_BLOCKS, 256, 0, stream>>>(hin, hbf, csr, off, W1 + L * 4096, ybuf, s1,
                                                 gid, (L == 0) ? pooled : nullptr);
        k_g2<<<AGG_BLOCKS, 256, 0, stream>>>(ybuf, s1, bn1g + L * 64, bn1b + L * 64,
                                             W2 + L * 4096, hbuf, s2);
        k_a2<<<AGG_BLOCKS, 256, 0, stream>>>(hbuf, hbf, s2, bn2g + L * 64, bn2b + L * 64,
                                             gid, pooled + (size_t)(L + 1) * NG * 64);
        hin = hbuf;
    }
    k_final<<<(NG * 16 + 255) / 256, 256, 0, stream>>>(pooled, pW, pb, out);
}

// Round 4
// 754.111 us; speedup vs baseline: 1.2627x; 1.2627x over previous
//
#include <hip/hip_runtime.h>
#include <math.h>

#define NN 100000
#define NE 1600000
#define NG 1000
#define BN_EPS 1e-5f
#define AGG_BLOCKS 2048
#define CAP 512      // per-wave LDS index cache (ints)
#define RNG 500      // nodes per bucket (200*500 == 100000)
#define NBUK 200
#define BB 512       // binning blocks
#define BCAP 12288   // per-bucket LDS edge capacity (mean 8000, +40 sigma)

typedef unsigned short ushort_t;
typedef unsigned int uint_t;

__device__ inline float bf2f(ushort_t u) {
    union { unsigned int i; float f; } c; c.i = ((unsigned int)u) << 16; return c.f;
}
__device__ inline ushort_t f2bf(float f) {
    union { float f; unsigned int i; } c; c.f = f;
    unsigned int u = c.i;
    u += 0x7FFFu + ((u >> 16) & 1u);   // RNE
    return (ushort_t)(u >> 16);
}

// ---------------- init ----------------

__global__ __launch_bounds__(256) void k_init(float* pooled, float* stats, int* bcnt) {
    int i = blockIdx.x * blockDim.x + threadIdx.x;
    int stride = gridDim.x * blockDim.x;
    for (int j = i; j < 5 * NG * 64; j += stride) pooled[j] = 0.f;
    for (int j = i; j < 1024; j += stride) stats[j] = 0.f;
    for (int j = i; j < NBUK; j += stride) bcnt[j] = 0;
}

__global__ __launch_bounds__(256) void k_f2bf(const float4* __restrict__ x, uint2* __restrict__ o) {
    int i = blockIdx.x * blockDim.x + threadIdx.x;
    int stride = gridDim.x * blockDim.x;
    for (int j = i; j < NN * 16; j += stride) {
        float4 v = x[j];
        uint2 r;
        r.x = (uint_t)f2bf(v.x) | ((uint_t)f2bf(v.y) << 16);
        r.y = (uint_t)f2bf(v.z) | ((uint_t)f2bf(v.w) << 16);
        o[j] = r;
    }
}

// ---------------- CSR build: block-local counting sort ----------------

__global__ __launch_bounds__(256) void k_cnt(const int* __restrict__ dst,
                                             int* __restrict__ cmat, int* __restrict__ bcnt) {
    __shared__ int l[NBUK];
    int b = blockIdx.x;
    for (int t = threadIdx.x; t < NBUK; t += 256) l[t] = 0;
    __syncthreads();
    int per = (NE + BB - 1) / BB;
    int s = b * per, e = min(NE, s + per);
    for (int i = s + threadIdx.x; i < e; i += 256) atomicAdd(&l[dst[i] / RNG], 1);
    __syncthreads();
    for (int t = threadIdx.x; t < NBUK; t += 256) {
        cmat[b * NBUK + t] = l[t];
        if (l[t]) atomicAdd(&bcnt[t], l[t]);
    }
}

__global__ __launch_bounds__(256) void k_bucket_scan(const int* __restrict__ bcnt,
                                                     int* __restrict__ boff) {
    __shared__ int s[256];
    int t = threadIdx.x;
    int v = (t < NBUK) ? bcnt[t] : 0;
    s[t] = v;
    __syncthreads();
    for (int o = 1; o < 256; o <<= 1) {
        int x = (t >= o) ? s[t - o] : 0;
        __syncthreads();
        s[t] += x;
        __syncthreads();
    }
    if (t < NBUK) boff[t] = s[t] - v;
    if (t == 0) boff[NBUK] = NE;
}

// per-bucket column scan of cmat -> per-(block,bucket) write windows
__global__ __launch_bounds__(256) void k_boffscan(const int* __restrict__ cmat,
                                                  const int* __restrict__ boff,
                                                  int* __restrict__ wmat) {
    __shared__ int s[256];
    int k = blockIdx.x;
    int t = threadIdx.x;
    int c0 = cmat[(2 * t) * NBUK + k];
    int c1 = cmat[(2 * t + 1) * NBUK + k];
    int sum = c0 + c1;
    s[t] = sum;
    __syncthreads();
    for (int o = 1; o < 256; o <<= 1) {
        int x = (t >= o) ? s[t - o] : 0;
        __syncthreads();
        s[t] += x;
        __syncthreads();
    }
    int excl = s[t] - sum + boff[k];
    wmat[(2 * t) * NBUK + k] = excl;
    wmat[(2 * t + 1) * NBUK + k] = excl + c0;
}

__global__ __launch_bounds__(256) void k_bin2(const int* __restrict__ src, const int* __restrict__ dst,
                                              const int* __restrict__ wmat, uint_t* __restrict__ binned) {
    __shared__ int l[NBUK];
    int b = blockIdx.x;
    for (int t = threadIdx.x; t < NBUK; t += 256) l[t] = 0;
    __syncthreads();
    int per = (NE + BB - 1) / BB;
    int s = b * per, e = min(NE, s + per);
    for (int i = s + threadIdx.x; i < e; i += 256) {
        int d = dst[i];
        int k = d / RNG;
        int ldst = d - k * RNG;
        int r = atomicAdd(&l[k], 1);
        binned[wmat[b * NBUK + k] + r] = ((uint_t)ldst << 17) | (uint_t)src[i];
    }
}

// one block per bucket: LDS counting-sort -> off[] + csr[]
__global__ __launch_bounds__(256) void k_bucket_finish(
    const uint_t* __restrict__ binned, const int* __restrict__ boff,
    int* __restrict__ off, int* __restrict__ csr)
{
    __shared__ uint_t ebuf[BCAP];
    __shared__ int cnt[512];
    __shared__ int a[256];
    __shared__ int wpos[RNG];
    int k = blockIdx.x;
    int t = threadIdx.x;
    int e0 = boff[k], e1 = boff[k + 1];
    int m = e1 - e0;
    bool inl = (m <= BCAP);

    cnt[t] = 0; cnt[t + 256] = 0;
    if (inl) for (int i = t; i < m; i += 256) ebuf[i] = binned[e0 + i];
    __syncthreads();
    for (int i = t; i < m; i += 256) {
        uint_t v = inl ? ebuf[i] : binned[e0 + i];
        atomicAdd(&cnt[v >> 17], 1);
    }
    __syncthreads();
    int c0 = cnt[2 * t], c1 = cnt[2 * t + 1];
    int sum = c0 + c1;
    a[t] = sum;
    __syncthreads();
    for (int o = 1; o < 256; o <<= 1) {
        int x = (t >= o) ? a[t - o] : 0;
        __syncthreads();
        a[t] += x;
        __syncthreads();
    }
    int excl = a[t] - sum;
    int base = k * RNG;
    if (2 * t < RNG) {
        off[base + 2 * t] = e0 + excl;
        wpos[2 * t] = excl;
    }
    if (2 * t + 1 < RNG) {
        off[base + 2 * t + 1] = e0 + excl + c0;
        wpos[2 * t + 1] = excl + c0;
    }
    if (k == NBUK - 1 && t == 0) off[NN] = NE;
    __syncthreads();
    for (int i = t; i < m; i += 256) {
        uint_t v = inl ? ebuf[i] : binned[e0 + i];
        int ldst = (int)(v >> 17);
        int r = atomicAdd(&wpos[ldst], 1);
        csr[e0 + r] = (int)(v & 0x1FFFFu);
    }
}

// ---------------- fused layer kernels ----------------

__global__ __launch_bounds__(256) void k_agg_g1(
    const float* __restrict__ h, const ushort_t* __restrict__ hb,
    const int* __restrict__ csr, const int* __restrict__ off,
    const float* __restrict__ W1, float* __restrict__ y,
    float* __restrict__ stats1,
    const int* __restrict__ gid, float* __restrict__ pool0)
{
    __shared__ __align__(16) float buf[4][64];
    __shared__ int sidx[4][CAP];
    __shared__ float sred[128];
    int lane = threadIdx.x & 63;
    int wslot = threadIdx.x >> 6;
    int wid = blockIdx.x * 4 + wslot;
    int nw = AGG_BLOCKS * 4;
    int chunk = (NN + nw - 1) / nw;
    int n0 = wid * chunk, n1 = min(NN, n0 + chunk);

    float Wc[64];
#pragma unroll
    for (int k = 0; k < 64; k++) Wc[k] = W1[k * 64 + lane];

    float ls = 0.f, lss = 0.f;

    if (n0 < n1) {
        int e0 = off[n0];
        int eEnd = off[n1];
        int tot = eEnd - e0;
        int lim = min(tot, CAP);
        for (int t = lane; t < lim; t += 64) sidx[wslot][t] = csr[e0 + t];

        int curg = -1;
        float pacc = 0.f;

        for (int n = n0; n < n1; ++n) {
            float acc = h[(size_t)n * 64 + lane];
            if (pool0) {
                int g = gid[n];
                if (g != curg) {
                    if (curg >= 0) atomicAdd(&pool0[curg * 64 + lane], pacc);
                    curg = g; pacc = 0.f;
                }
                pacc += acc;
            }
            int s0 = off[n] - e0, s1 = off[n + 1] - e0;
            float a1 = 0.f, a2 = 0.f, a3 = 0.f;
            float a4 = 0.f, a5 = 0.f, a6 = 0.f, a7 = 0.f;
            int j = s0;
            if (s1 <= lim) {
                for (; j + 8 <= s1; j += 8) {
                    int i0 = sidx[wslot][j],     i1 = sidx[wslot][j + 1],
                        i2 = sidx[wslot][j + 2], i3 = sidx[wslot][j + 3],
                        i4 = sidx[wslot][j + 4], i5 = sidx[wslot][j + 5],
                        i6 = sidx[wslot][j + 6], i7 = sidx[wslot][j + 7];
                    float v0 = bf2f(hb[(size_t)i0 * 64 + lane]);
                    float v1 = bf2f(hb[(size_t)i1 * 64 + lane]);
                    float v2 = bf2f(hb[(size_t)i2 * 64 + lane]);
                    float v3 = bf2f(hb[(size_t)i3 * 64 + lane]);
                    float v4 = bf2f(hb[(size_t)i4 * 64 + lane]);
                    float v5 = bf2f(hb[(size_t)i5 * 64 + lane]);
                    float v6 = bf2f(hb[(size_t)i6 * 64 + lane]);
                    float v7 = bf2f(hb[(size_t)i7 * 64 + lane]);
                    acc += v0; a1 += v1; a2 += v2; a3 += v3;
                    a4 += v4; a5 += v5; a6 += v6; a7 += v7;
                }
                for (; j + 4 <= s1; j += 4) {
                    int i0 = sidx[wslot][j],     i1 = sidx[wslot][j + 1],
                        i2 = sidx[wslot][j + 2], i3 = sidx[wslot][j + 3];
                    float v0 = bf2f(hb[(size_t)i0 * 64 + lane]);
                    float v1 = bf2f(hb[(size_t)i1 * 64 + lane]);
                    float v2 = bf2f(hb[(size_t)i2 * 64 + lane]);
                    float v3 = bf2f(hb[(size_t)i3 * 64 + lane]);
                    acc += v0; a1 += v1; a2 += v2; a3 += v3;
                }
                for (; j < s1; ++j) acc += bf2f(hb[(size_t)sidx[wslot][j] * 64 + lane]);
            } else {
                for (; j + 4 <= s1; j += 4) {
                    int i0 = csr[e0 + j],     i1 = csr[e0 + j + 1],
                        i2 = csr[e0 + j + 2], i3 = csr[e0 + j + 3];
                    float v0 = bf2f(hb[(size_t)i0 * 64 + lane]);
                    float v1 = bf2f(hb[(size_t)i1 * 64 + lane]);
                    float v2 = bf2f(hb[(size_t)i2 * 64 + lane]);
                    float v3 = bf2f(hb[(size_t)i3 * 64 + lane]);
                    acc += v0; a1 += v1; a2 += v2; a3 += v3;
                }
                for (; j < s1; ++j) acc += bf2f(hb[(size_t)csr[e0 + j] * 64 + lane]);
            }
            acc += ((a1 + a2) + (a3 + a4)) + ((a5 + a6) + a7);

            buf[wslot][lane] = acc;
            float yl = 0.f;
#pragma unroll
            for (int k = 0; k < 16; k++) {
                float4 z4 = *(const float4*)&buf[wslot][k * 4];
                yl = fmaf(z4.x, Wc[4 * k], yl);
                yl = fmaf(z4.y, Wc[4 * k + 1], yl);
                yl = fmaf(z4.z, Wc[4 * k + 2], yl);
                yl = fmaf(z4.w, Wc[4 * k + 3], yl);
            }
            y[(size_t)n * 64 + lane] = yl;
            ls += yl;
            lss += yl * yl;
        }
        if (pool0 && curg >= 0) atomicAdd(&pool0[curg * 64 + lane], pacc);
    }

    if (threadIdx.x < 128) sred[threadIdx.x] = 0.f;
    __syncthreads();
    atomicAdd(&sred[lane], ls);
    atomicAdd(&sred[64 + lane], lss);
    __syncthreads();
    if (threadIdx.x < 128) atomicAdd(&stats1[threadIdx.x], sred[threadIdx.x]);
}

__global__ __launch_bounds__(256) void k_g2(
    const float* __restrict__ y, const float* __restrict__ stats1,
    const float* __restrict__ g1, const float* __restrict__ b1,
    const float* __restrict__ W2, float* __restrict__ z,
    float* __restrict__ stats2)
{
    __shared__ __align__(16) float buf[4][4][64];
    __shared__ float sred[128];
    int lane = threadIdx.x & 63;
    int wslot = threadIdx.x >> 6;
    int wid = blockIdx.x * 4 + wslot;
    int nw = AGG_BLOCKS * 4;
    int chunk = (NN + nw - 1) / nw;
    int n0 = wid * chunk, n1 = min(NN, n0 + chunk);

    float mean = stats1[lane] * (1.f / NN);
    float var  = stats1[64 + lane] * (1.f / NN) - mean * mean;
    float sc = rsqrtf(var + BN_EPS) * g1[lane];
    float sh = b1[lane] - mean * sc;

    float Wc[64];
#pragma unroll
    for (int k = 0; k < 64; k++) Wc[k] = W2[k * 64 + lane];

    float ls = 0.f, lss = 0.f;
    if (n0 < n1) {
        int n = n0;
        for (; n + 4 <= n1; n += 4) {
            float v0 = fmaxf(fmaf(y[(size_t)n * 64 + lane], sc, sh), 0.f);
            float v1 = fmaxf(fmaf(y[(size_t)(n + 1) * 64 + lane], sc, sh), 0.f);
            float v2 = fmaxf(fmaf(y[(size_t)(n + 2) * 64 + lane], sc, sh), 0.f);
            float v3 = fmaxf(fmaf(y[(size_t)(n + 3) * 64 + lane], sc, sh), 0.f);
            buf[wslot][0][lane] = v0;
            buf[wslot][1][lane] = v1;
            buf[wslot][2][lane] = v2;
            buf[wslot][3][lane] = v3;
#pragma unroll
            for (int r = 0; r < 4; ++r) {
                float zl = 0.f;
#pragma unroll
                for (int k = 0; k < 16; k++) {
                    float4 t4 = *(const float4*)&buf[wslot][r][k * 4];
                    zl = fmaf(t4.x, Wc[4 * k], zl);
                    zl = fmaf(t4.y, Wc[4 * k + 1], zl);
                    zl = fmaf(t4.z, Wc[4 * k + 2], zl);
                    zl = fmaf(t4.w, Wc[4 * k + 3], zl);
                }
                z[(size_t)(n + r) * 64 + lane] = zl;
                ls += zl;
                lss += zl * zl;
            }
        }
        for (; n < n1; ++n) {
            float v = fmaxf(fmaf(y[(size_t)n * 64 + lane], sc, sh), 0.f);
            buf[wslot][0][lane] = v;
            float zl = 0.f;
#pragma unroll
            for (int k = 0; k < 16; k++) {
                float4 t4 = *(const float4*)&buf[wslot][0][k * 4];
                zl = fmaf(t4.x, Wc[4 * k], zl);
                zl = fmaf(t4.y, Wc[4 * k + 1], zl);
                zl = fmaf(t4.z, Wc[4 * k + 2], zl);
                zl = fmaf(t4.w, Wc[4 * k + 3], zl);
            }
            z[(size_t)n * 64 + lane] = zl;
            ls += zl;
            lss += zl * zl;
        }
    }

    if (threadIdx.x < 128) sred[threadIdx.x] = 0.f;
    __syncthreads();
    atomicAdd(&sred[lane], ls);
    atomicAdd(&sred[64 + lane], lss);
    __syncthreads();
    if (threadIdx.x < 128) atomicAdd(&stats2[threadIdx.x], sred[threadIdx.x]);
}

__global__ __launch_bounds__(256) void k_a2(
    float* __restrict__ z,
    ushort_t* __restrict__ hb,
    const float* __restrict__ stats2,
    const float* __restrict__ g2, const float* __restrict__ b2,
    const int* __restrict__ gid, float* __restrict__ pool)
{
    int lane = threadIdx.x & 63;
    int wslot = threadIdx.x >> 6;
    int wid = blockIdx.x * 4 + wslot;
    int nw = AGG_BLOCKS * 4;
    int chunk = (NN + nw - 1) / nw;
    int n0 = wid * chunk, n1 = min(NN, n0 + chunk);
    if (n0 >= n1) return;

    float mean = stats2[lane] * (1.f / NN);
    float var  = stats2[64 + lane] * (1.f / NN) - mean * mean;
    float sc = rsqrtf(var + BN_EPS) * g2[lane];
    float sh = b2[lane] - mean * sc;

    int curg = -1;
    float pacc = 0.f;
    int n = n0;
    for (; n + 4 <= n1; n += 4) {
        float z0 = z[(size_t)n * 64 + lane];
        float z1 = z[(size_t)(n + 1) * 64 + lane];
        float z2v = z[(size_t)(n + 2) * 64 + lane];
        float z3 = z[(size_t)(n + 3) * 64 + lane];
        int g0 = gid[n], g1v = gid[n + 1], g2v = gid[n + 2], g3 = gid[n + 3];
        float vv[4] = {z0, z1, z2v, z3};
        int gg[4] = {g0, g1v, g2v, g3};
#pragma unroll
        for (int r = 0; r < 4; ++r) {
            float v = fmaxf(fmaf(vv[r], sc, sh), 0.f);
            z[(size_t)(n + r) * 64 + lane] = v;
            hb[(size_t)(n + r) * 64 + lane] = f2bf(v);
            if (gg[r] != curg) {
                if (curg >= 0) atomicAdd(&pool[curg * 64 + lane], pacc);
                curg = gg[r]; pacc = 0.f;
            }
            pacc += v;
        }
    }
    for (; n < n1; ++n) {
        float v = fmaxf(fmaf(z[(size_t)n * 64 + lane], sc, sh), 0.f);
        z[(size_t)n * 64 + lane] = v;
        hb[(size_t)n * 64 + lane] = f2bf(v);
        int g = gid[n];
        if (g != curg) {
            if (curg >= 0) atomicAdd(&pool[curg * 64 + lane], pacc);
            curg = g; pacc = 0.f;
        }
        pacc += v;
    }
    if (curg >= 0) atomicAdd(&pool[curg * 64 + lane], pacc);
}

// ---------------- epilogue ----------------

__global__ __launch_bounds__(256) void k_final(
    const float* __restrict__ pooled, const float* __restrict__ pW,
    const float* __restrict__ pb, float* __restrict__ out)
{
    int t = blockIdx.x * blockDim.x + threadIdx.x;
    int g = t >> 4;
    int c = t & 15;
    if (g >= NG) return;
    float acc = 0.f;
#pragma unroll
    for (int i = 0; i < 5; i++) {
        const float* P = pooled + (size_t)i * NG * 64 + g * 64;
        const float* W = pW + i * 64 * 16;
        float a = 0.f;
#pragma unroll
        for (int k = 0; k < 64; k++) a += P[k] * W[k * 16 + c];
        acc += a + pb[i * 16 + c];
    }
    float m = acc;
    for (int o = 1; o < 16; o <<= 1) m = fmaxf(m, __shfl_xor(m, o, 16));
    float e = expf(acc - m);
    float s = e;
    for (int o = 1; o < 16; o <<= 1) s += __shfl_xor(s, o, 16);
    out[g * 16 + c] = acc - m - logf(s);
}

// ---------------- launch ----------------

extern "C" void kernel_launch(void* const* d_in, const int* in_sizes, int n_in,
                              void* d_out, int out_size, void* d_ws, size_t ws_size,
                              hipStream_t stream) {
    const float* feat = (const float*)d_in[0];
    const float* W1   = (const float*)d_in[1];
    const float* W2   = (const float*)d_in[2];
    const float* bn1g = (const float*)d_in[3];
    const float* bn1b = (const float*)d_in[4];
    const float* bn2g = (const float*)d_in[5];
    const float* bn2b = (const float*)d_in[6];
    const float* pW   = (const float*)d_in[7];
    const float* pb   = (const float*)d_in[8];
    const int* src = (const int*)d_in[9];
    const int* dst = (const int*)d_in[10];
    const int* gid = (const int*)d_in[11];
    float* out = (float*)d_out;

    char* ws = (char*)d_ws;
    size_t o = 0;
    auto alloc = [&](size_t bytes) {
        void* p = ws + o;
        o += (bytes + 255) & ~(size_t)255;
        return p;
    };
    float* hbuf   = (float*)alloc((size_t)NN * 64 * 4);
    float* ybuf   = (float*)alloc((size_t)NN * 64 * 4);
    ushort_t* hbf = (ushort_t*)alloc((size_t)NN * 64 * 2);
    float* pooled = (float*)alloc((size_t)5 * NG * 64 * 4);
    float* stats  = (float*)alloc(1024 * 4);
    int* off  = (int*)alloc((size_t)(NN + 1) * 4);
    int* csr  = (int*)alloc((size_t)NE * 4);
    uint_t* binned = (uint_t*)alloc((size_t)NE * 4);
    int* cmat = (int*)alloc((size_t)BB * NBUK * 4);
    int* wmat = (int*)alloc((size_t)BB * NBUK * 4);
    int* bcnt = (int*)alloc(NBUK * 4);
    int* boff = (int*)alloc((NBUK + 1) * 4);

    k_init<<<256, 256, 0, stream>>>(pooled, stats, bcnt);
    k_f2bf<<<1024, 256, 0, stream>>>((const float4*)feat, (uint2*)hbf);
    k_cnt<<<BB, 256, 0, stream>>>(dst, cmat, bcnt);
    k_bucket_scan<<<1, 256, 0, stream>>>(bcnt, boff);
    k_boffscan<<<NBUK, 256, 0, stream>>>(cmat, boff, wmat);
    k_bin2<<<BB, 256, 0, stream>>>(src, dst, wmat, binned);
    k_bucket_finish<<<NBUK, 256, 0, stream>>>(binned, boff, off, csr);

    const float* hin = feat;
    for (int L = 0; L < 4; ++L) {
        float* s1 = stats + L * 256;
        float* s2 = s1 + 128;
        k_agg_g1<<<AGG_BLOCKS, 256, 0, stream>>>(hin, hbf, csr, off, W1 + L * 4096, ybuf, s1,
                                                 gid, (L == 0) ? pooled : nullptr);
        k_g2<<<AGG_BLOCKS, 256, 0, stream>>>(ybuf, s1, bn1g + L * 64, bn1b + L * 64,
                                             W2 + L * 4096, hbuf, s2);
        k_a2<<<AGG_BLOCKS, 256, 0, stream>>>(hbuf, hbf, s2, bn2g + L * 64, bn2b + L * 64,
                                             gid, pooled + (size_t)(L + 1) * NG * 64);
        hin = hbuf;
    }
    k_final<<<(NG * 16 + 255) / 256, 256, 0, stream>>>(pooled, pW, pb, out);
}

// Round 5
// 734.581 us; speedup vs baseline: 1.2963x; 1.0266x over previous
//
#include <hip/hip_runtime.h>
#include <math.h>

#define NN 100000
#define NE 1600000
#define NG 1000
#define BN_EPS 1e-5f
#define AGG_BLOCKS 2048
#define CAP 512      // per-wave LDS index cache (ints)
#define RNG 500      // nodes per bucket (200*500 == 100000)
#define NBUK 200
#define BB 512       // binning blocks
#define BCAP 12288   // per-bucket LDS edge capacity

typedef unsigned short ushort_t;
typedef unsigned int uint_t;

__device__ inline float bf2f(ushort_t u) {
    union { unsigned int i; float f; } c; c.i = ((unsigned int)u) << 16; return c.f;
}
__device__ inline ushort_t f2bf(float f) {
    union { float f; unsigned int i; } c; c.f = f;
    unsigned int u = c.i;
    u += 0x7FFFu + ((u >> 16) & 1u);   // RNE
    return (ushort_t)(u >> 16);
}
__device__ inline float affop(float v, float sc, float sh, int dorelu) {
    float t = fmaf(v, sc, sh);
    return dorelu ? fmaxf(t, 0.f) : t;
}

// ---------------- init ----------------

__global__ __launch_bounds__(256) void k_init(float* pooled, float* stats, int* bcnt) {
    int i = blockIdx.x * blockDim.x + threadIdx.x;
    int stride = gridDim.x * blockDim.x;
    for (int j = i; j < 5 * NG * 64; j += stride) pooled[j] = 0.f;
    for (int j = i; j < 1024; j += stride) stats[j] = 0.f;
    for (int j = i; j < NBUK; j += stride) bcnt[j] = 0;
}

__global__ __launch_bounds__(256) void k_f2bf(const float4* __restrict__ x, uint2* __restrict__ o) {
    int i = blockIdx.x * blockDim.x + threadIdx.x;
    int stride = gridDim.x * blockDim.x;
    for (int j = i; j < NN * 16; j += stride) {
        float4 v = x[j];
        uint2 r;
        r.x = (uint_t)f2bf(v.x) | ((uint_t)f2bf(v.y) << 16);
        r.y = (uint_t)f2bf(v.z) | ((uint_t)f2bf(v.w) << 16);
        o[j] = r;
    }
}

// ---------------- CSR build: block-local counting sort ----------------

__global__ __launch_bounds__(256) void k_cnt(const int* __restrict__ dst,
                                             int* __restrict__ cmat, int* __restrict__ bcnt) {
    __shared__ int l[NBUK];
    int b = blockIdx.x;
    for (int t = threadIdx.x; t < NBUK; t += 256) l[t] = 0;
    __syncthreads();
    int per = (NE + BB - 1) / BB;
    int s = b * per, e = min(NE, s + per);
    for (int i = s + threadIdx.x; i < e; i += 256) atomicAdd(&l[dst[i] / RNG], 1);
    __syncthreads();
    for (int t = threadIdx.x; t < NBUK; t += 256) {
        cmat[b * NBUK + t] = l[t];
        if (l[t]) atomicAdd(&bcnt[t], l[t]);
    }
}

__global__ __launch_bounds__(256) void k_bucket_scan(const int* __restrict__ bcnt,
                                                     int* __restrict__ boff) {
    __shared__ int s[256];
    int t = threadIdx.x;
    int v = (t < NBUK) ? bcnt[t] : 0;
    s[t] = v;
    __syncthreads();
    for (int o = 1; o < 256; o <<= 1) {
        int x = (t >= o) ? s[t - o] : 0;
        __syncthreads();
        s[t] += x;
        __syncthreads();
    }
    if (t < NBUK) boff[t] = s[t] - v;
    if (t == 0) boff[NBUK] = NE;
}

__global__ __launch_bounds__(256) void k_boffscan(const int* __restrict__ cmat,
                                                  const int* __restrict__ boff,
                                                  int* __restrict__ wmat) {
    __shared__ int s[256];
    int k = blockIdx.x;
    int t = threadIdx.x;
    int c0 = cmat[(2 * t) * NBUK + k];
    int c1 = cmat[(2 * t + 1) * NBUK + k];
    int sum = c0 + c1;
    s[t] = sum;
    __syncthreads();
    for (int o = 1; o < 256; o <<= 1) {
        int x = (t >= o) ? s[t - o] : 0;
        __syncthreads();
        s[t] += x;
        __syncthreads();
    }
    int excl = s[t] - sum + boff[k];
    wmat[(2 * t) * NBUK + k] = excl;
    wmat[(2 * t + 1) * NBUK + k] = excl + c0;
}

__global__ __launch_bounds__(256) void k_bin2(const int* __restrict__ src, const int* __restrict__ dst,
                                              const int* __restrict__ wmat, uint_t* __restrict__ binned) {
    __shared__ int l[NBUK];
    int b = blockIdx.x;
    for (int t = threadIdx.x; t < NBUK; t += 256) l[t] = 0;
    __syncthreads();
    int per = (NE + BB - 1) / BB;
    int s = b * per, e = min(NE, s + per);
    for (int i = s + threadIdx.x; i < e; i += 256) {
        int d = dst[i];
        int k = d / RNG;
        int ldst = d - k * RNG;
        int r = atomicAdd(&l[k], 1);
        binned[wmat[b * NBUK + k] + r] = ((uint_t)ldst << 17) | (uint_t)src[i];
    }
}

__global__ __launch_bounds__(256) void k_bucket_finish(
    const uint_t* __restrict__ binned, const int* __restrict__ boff,
    int* __restrict__ off, int* __restrict__ csr)
{
    __shared__ uint_t ebuf[BCAP];
    __shared__ int cnt[512];
    __shared__ int a[256];
    __shared__ int wpos[RNG];
    int k = blockIdx.x;
    int t = threadIdx.x;
    int e0 = boff[k], e1 = boff[k + 1];
    int m = e1 - e0;
    bool inl = (m <= BCAP);

    cnt[t] = 0; cnt[t + 256] = 0;
    if (inl) for (int i = t; i < m; i += 256) ebuf[i] = binned[e0 + i];
    __syncthreads();
    for (int i = t; i < m; i += 256) {
        uint_t v = inl ? ebuf[i] : binned[e0 + i];
        atomicAdd(&cnt[v >> 17], 1);
    }
    __syncthreads();
    int c0 = cnt[2 * t], c1 = cnt[2 * t + 1];
    int sum = c0 + c1;
    a[t] = sum;
    __syncthreads();
    for (int o = 1; o < 256; o <<= 1) {
        int x = (t >= o) ? a[t - o] : 0;
        __syncthreads();
        a[t] += x;
        __syncthreads();
    }
    int excl = a[t] - sum;
    int base = k * RNG;
    if (2 * t < RNG) { off[base + 2 * t] = e0 + excl; wpos[2 * t] = excl; }
    if (2 * t + 1 < RNG) { off[base + 2 * t + 1] = e0 + excl + c0; wpos[2 * t + 1] = excl + c0; }
    if (k == NBUK - 1 && t == 0) off[NN] = NE;
    __syncthreads();
    for (int i = t; i < m; i += 256) {
        uint_t v = inl ? ebuf[i] : binned[e0 + i];
        int ldst = (int)(v >> 17);
        int r = atomicAdd(&wpos[ldst], 1);
        csr[e0 + r] = (int)(v & 0x1FFFFu);
    }
}

// ---------------- fused layer kernels ----------------
// k_agg: on-the-fly affine(+relu) of bf16 input (folds prev layer's BN2+ReLU),
// GIN aggregation, GEMM1, BN1 stats, pool of h_L.

__global__ __launch_bounds__(256) void k_agg(
    const ushort_t* __restrict__ zb,
    const float* __restrict__ stats2p, const float* __restrict__ g2p, const float* __restrict__ b2p,
    int dorelu,
    const int* __restrict__ csr, const int* __restrict__ off,
    const float* __restrict__ W1, ushort_t* __restrict__ yb,
    float* __restrict__ stats1,
    const int* __restrict__ gid, float* __restrict__ poolL)
{
    __shared__ __align__(16) float buf[4][64];
    __shared__ int sidx[4][CAP];
    __shared__ float sred[128];
    int lane = threadIdx.x & 63;
    int wslot = threadIdx.x >> 6;
    int wid = blockIdx.x * 4 + wslot;
    int nw = AGG_BLOCKS * 4;
    int chunk = (NN + nw - 1) / nw;
    int n0 = wid * chunk, n1 = min(NN, n0 + chunk);

    float sc = 1.f, sh = 0.f;
    if (stats2p) {
        float mean = stats2p[lane] * (1.f / NN);
        float var  = stats2p[64 + lane] * (1.f / NN) - mean * mean;
        sc = rsqrtf(var + BN_EPS) * g2p[lane];
        sh = b2p[lane] - mean * sc;
    }

    float Wc[64];
#pragma unroll
    for (int k = 0; k < 64; k++) Wc[k] = W1[k * 64 + lane];

    float ls = 0.f, lss = 0.f;

    if (n0 < n1) {
        int e0 = off[n0];
        int eEnd = off[n1];
        int tot = eEnd - e0;
        int lim = min(tot, CAP);
        for (int t = lane; t < lim; t += 64) sidx[wslot][t] = csr[e0 + t];

        int curg = -1;
        float pacc = 0.f;

        for (int n = n0; n < n1; ++n) {
            float hself = affop(bf2f(zb[(size_t)n * 64 + lane]), sc, sh, dorelu);
            int g = gid[n];
            if (g != curg) {
                if (curg >= 0) atomicAdd(&poolL[curg * 64 + lane], pacc);
                curg = g; pacc = 0.f;
            }
            pacc += hself;

            float acc = hself;
            int s0 = off[n] - e0, s1 = off[n + 1] - e0;
            float a1 = 0.f, a2 = 0.f, a3 = 0.f;
            float a4 = 0.f, a5 = 0.f, a6 = 0.f, a7 = 0.f;
            int j = s0;
            if (s1 <= lim) {
                for (; j + 8 <= s1; j += 8) {
                    int i0 = sidx[wslot][j],     i1 = sidx[wslot][j + 1],
                        i2 = sidx[wslot][j + 2], i3 = sidx[wslot][j + 3],
                        i4 = sidx[wslot][j + 4], i5 = sidx[wslot][j + 5],
                        i6 = sidx[wslot][j + 6], i7 = sidx[wslot][j + 7];
                    float v0 = bf2f(zb[(size_t)i0 * 64 + lane]);
                    float v1 = bf2f(zb[(size_t)i1 * 64 + lane]);
                    float v2 = bf2f(zb[(size_t)i2 * 64 + lane]);
                    float v3 = bf2f(zb[(size_t)i3 * 64 + lane]);
                    float v4 = bf2f(zb[(size_t)i4 * 64 + lane]);
                    float v5 = bf2f(zb[(size_t)i5 * 64 + lane]);
                    float v6 = bf2f(zb[(size_t)i6 * 64 + lane]);
                    float v7 = bf2f(zb[(size_t)i7 * 64 + lane]);
                    acc += affop(v0, sc, sh, dorelu); a1 += affop(v1, sc, sh, dorelu);
                    a2  += affop(v2, sc, sh, dorelu); a3 += affop(v3, sc, sh, dorelu);
                    a4  += affop(v4, sc, sh, dorelu); a5 += affop(v5, sc, sh, dorelu);
                    a6  += affop(v6, sc, sh, dorelu); a7 += affop(v7, sc, sh, dorelu);
                }
                for (; j + 4 <= s1; j += 4) {
                    int i0 = sidx[wslot][j],     i1 = sidx[wslot][j + 1],
                        i2 = sidx[wslot][j + 2], i3 = sidx[wslot][j + 3];
                    float v0 = bf2f(zb[(size_t)i0 * 64 + lane]);
                    float v1 = bf2f(zb[(size_t)i1 * 64 + lane]);
                    float v2 = bf2f(zb[(size_t)i2 * 64 + lane]);
                    float v3 = bf2f(zb[(size_t)i3 * 64 + lane]);
                    acc += affop(v0, sc, sh, dorelu); a1 += affop(v1, sc, sh, dorelu);
                    a2  += affop(v2, sc, sh, dorelu); a3 += affop(v3, sc, sh, dorelu);
                }
                for (; j < s1; ++j)
                    acc += affop(bf2f(zb[(size_t)sidx[wslot][j] * 64 + lane]), sc, sh, dorelu);
            } else {
                for (; j + 4 <= s1; j += 4) {
                    int i0 = csr[e0 + j],     i1 = csr[e0 + j + 1],
                        i2 = csr[e0 + j + 2], i3 = csr[e0 + j + 3];
                    float v0 = bf2f(zb[(size_t)i0 * 64 + lane]);
                    float v1 = bf2f(zb[(size_t)i1 * 64 + lane]);
                    float v2 = bf2f(zb[(size_t)i2 * 64 + lane]);
                    float v3 = bf2f(zb[(size_t)i3 * 64 + lane]);
                    acc += affop(v0, sc, sh, dorelu); a1 += affop(v1, sc, sh, dorelu);
                    a2  += affop(v2, sc, sh, dorelu); a3 += affop(v3, sc, sh, dorelu);
                }
                for (; j < s1; ++j)
                    acc += affop(bf2f(zb[(size_t)csr[e0 + j] * 64 + lane]), sc, sh, dorelu);
            }
            acc += ((a1 + a2) + (a3 + a4)) + ((a5 + a6) + a7);

            buf[wslot][lane] = acc;
            float yl = 0.f;
#pragma unroll
            for (int k = 0; k < 16; k++) {
                float4 z4 = *(const float4*)&buf[wslot][k * 4];
                yl = fmaf(z4.x, Wc[4 * k], yl);
                yl = fmaf(z4.y, Wc[4 * k + 1], yl);
                yl = fmaf(z4.z, Wc[4 * k + 2], yl);
                yl = fmaf(z4.w, Wc[4 * k + 3], yl);
            }
            yb[(size_t)n * 64 + lane] = f2bf(yl);
            ls += yl;
            lss += yl * yl;
        }
        if (curg >= 0) atomicAdd(&poolL[curg * 64 + lane], pacc);
    }

    if (threadIdx.x < 128) sred[threadIdx.x] = 0.f;
    __syncthreads();
    atomicAdd(&sred[lane], ls);
    atomicAdd(&sred[64 + lane], lss);
    __syncthreads();
    if (threadIdx.x < 128) atomicAdd(&stats1[threadIdx.x], sred[threadIdx.x]);
}

// k_g2: BN1 apply + ReLU + GEMM2 + BN2 stats; bf16 in/out.

__global__ __launch_bounds__(256) void k_g2(
    const ushort_t* __restrict__ yb, const float* __restrict__ stats1,
    const float* __restrict__ g1, const float* __restrict__ b1,
    const float* __restrict__ W2, ushort_t* __restrict__ zb,
    float* __restrict__ stats2)
{
    __shared__ __align__(16) float buf[4][4][64];
    __shared__ float sred[128];
    int lane = threadIdx.x & 63;
    int wslot = threadIdx.x >> 6;
    int wid = blockIdx.x * 4 + wslot;
    int nw = AGG_BLOCKS * 4;
    int chunk = (NN + nw - 1) / nw;
    int n0 = wid * chunk, n1 = min(NN, n0 + chunk);

    float mean = stats1[lane] * (1.f / NN);
    float var  = stats1[64 + lane] * (1.f / NN) - mean * mean;
    float sc = rsqrtf(var + BN_EPS) * g1[lane];
    float sh = b1[lane] - mean * sc;

    float Wc[64];
#pragma unroll
    for (int k = 0; k < 64; k++) Wc[k] = W2[k * 64 + lane];

    float ls = 0.f, lss = 0.f;
    if (n0 < n1) {
        int n = n0;
        for (; n + 4 <= n1; n += 4) {
            float v0 = fmaxf(fmaf(bf2f(yb[(size_t)n * 64 + lane]), sc, sh), 0.f);
            float v1 = fmaxf(fmaf(bf2f(yb[(size_t)(n + 1) * 64 + lane]), sc, sh), 0.f);
            float v2 = fmaxf(fmaf(bf2f(yb[(size_t)(n + 2) * 64 + lane]), sc, sh), 0.f);
            float v3 = fmaxf(fmaf(bf2f(yb[(size_t)(n + 3) * 64 + lane]), sc, sh), 0.f);
            buf[wslot][0][lane] = v0;
            buf[wslot][1][lane] = v1;
            buf[wslot][2][lane] = v2;
            buf[wslot][3][lane] = v3;
#pragma unroll
            for (int r = 0; r < 4; ++r) {
                float zl = 0.f;
#pragma unroll
                for (int k = 0; k < 16; k++) {
                    float4 t4 = *(const float4*)&buf[wslot][r][k * 4];
                    zl = fmaf(t4.x, Wc[4 * k], zl);
                    zl = fmaf(t4.y, Wc[4 * k + 1], zl);
                    zl = fmaf(t4.z, Wc[4 * k + 2], zl);
                    zl = fmaf(t4.w, Wc[4 * k + 3], zl);
                }
                zb[(size_t)(n + r) * 64 + lane] = f2bf(zl);
                ls += zl;
                lss += zl * zl;
            }
        }
        for (; n < n1; ++n) {
            float v = fmaxf(fmaf(bf2f(yb[(size_t)n * 64 + lane]), sc, sh), 0.f);
            buf[wslot][0][lane] = v;
            float zl = 0.f;
#pragma unroll
            for (int k = 0; k < 16; k++) {
                float4 t4 = *(const float4*)&buf[wslot][0][k * 4];
                zl = fmaf(t4.x, Wc[4 * k], zl);
                zl = fmaf(t4.y, Wc[4 * k + 1], zl);
                zl = fmaf(t4.z, Wc[4 * k + 2], zl);
                zl = fmaf(t4.w, Wc[4 * k + 3], zl);
            }
            zb[(size_t)n * 64 + lane] = f2bf(zl);
            ls += zl;
            lss += zl * zl;
        }
    }

    if (threadIdx.x < 128) sred[threadIdx.x] = 0.f;
    __syncthreads();
    atomicAdd(&sred[lane], ls);
    atomicAdd(&sred[64 + lane], lss);
    __syncthreads();
    if (threadIdx.x < 128) atomicAdd(&stats2[threadIdx.x], sred[threadIdx.x]);
}

// final hidden rep pooling (h_4)

__global__ __launch_bounds__(256) void k_pool4(
    const ushort_t* __restrict__ zb,
    const float* __restrict__ stats2, const float* __restrict__ g2, const float* __restrict__ b2,
    const int* __restrict__ gid, float* __restrict__ pool)
{
    int lane = threadIdx.x & 63;
    int wslot = threadIdx.x >> 6;
    int wid = blockIdx.x * 4 + wslot;
    int nw = gridDim.x * 4;
    int chunk = (NN + nw - 1) / nw;
    int n0 = wid * chunk, n1 = min(NN, n0 + chunk);
    if (n0 >= n1) return;

    float mean = stats2[lane] * (1.f / NN);
    float var  = stats2[64 + lane] * (1.f / NN) - mean * mean;
    float sc = rsqrtf(var + BN_EPS) * g2[lane];
    float sh = b2[lane] - mean * sc;

    int curg = -1;
    float pacc = 0.f;
    for (int n = n0; n < n1; ++n) {
        float v = fmaxf(fmaf(bf2f(zb[(size_t)n * 64 + lane]), sc, sh), 0.f);
        int g = gid[n];
        if (g != curg) {
            if (curg >= 0) atomicAdd(&pool[curg * 64 + lane], pacc);
            curg = g; pacc = 0.f;
        }
        pacc += v;
    }
    if (curg >= 0) atomicAdd(&pool[curg * 64 + lane], pacc);
}

// ---------------- epilogue ----------------

__global__ __launch_bounds__(256) void k_final(
    const float* __restrict__ pooled, const float* __restrict__ pW,
    const float* __restrict__ pb, float* __restrict__ out)
{
    int t = blockIdx.x * blockDim.x + threadIdx.x;
    int g = t >> 4;
    int c = t & 15;
    if (g >= NG) return;
    float acc = 0.f;
#pragma unroll
    for (int i = 0; i < 5; i++) {
        const float* P = pooled + (size_t)i * NG * 64 + g * 64;
        const float* W = pW + i * 64 * 16;
        float a = 0.f;
#pragma unroll
        for (int k = 0; k < 64; k++) a += P[k] * W[k * 16 + c];
        acc += a + pb[i * 16 + c];
    }
    float m = acc;
    for (int o = 1; o < 16; o <<= 1) m = fmaxf(m, __shfl_xor(m, o, 16));
    float e = expf(acc - m);
    float s = e;
    for (int o = 1; o < 16; o <<= 1) s += __shfl_xor(s, o, 16);
    out[g * 16 + c] = acc - m - logf(s);
}

// ---------------- launch ----------------

extern "C" void kernel_launch(void* const* d_in, const int* in_sizes, int n_in,
                              void* d_out, int out_size, void* d_ws, size_t ws_size,
                              hipStream_t stream) {
    const float* feat = (const float*)d_in[0];
    const float* W1   = (const float*)d_in[1];
    const float* W2   = (const float*)d_in[2];
    const float* bn1g = (const float*)d_in[3];
    const float* bn1b = (const float*)d_in[4];
    const float* bn2g = (const float*)d_in[5];
    const float* bn2b = (const float*)d_in[6];
    const float* pW   = (const float*)d_in[7];
    const float* pb   = (const float*)d_in[8];
    const int* src = (const int*)d_in[9];
    const int* dst = (const int*)d_in[10];
    const int* gid = (const int*)d_in[11];
    float* out = (float*)d_out;

    char* ws = (char*)d_ws;
    size_t o = 0;
    auto alloc = [&](size_t bytes) {
        void* p = ws + o;
        o += (bytes + 255) & ~(size_t)255;
        return p;
    };
    ushort_t* zb  = (ushort_t*)alloc((size_t)NN * 64 * 2);   // layer input (pre-affine), bf16
    ushort_t* yb  = (ushort_t*)alloc((size_t)NN * 64 * 2);   // y = a@W1, bf16
    float* pooled = (float*)alloc((size_t)5 * NG * 64 * 4);
    float* stats  = (float*)alloc(1024 * 4);
    int* off  = (int*)alloc((size_t)(NN + 1) * 4);
    int* csr  = (int*)alloc((size_t)NE * 4);
    uint_t* binned = (uint_t*)alloc((size_t)NE * 4);
    int* cmat = (int*)alloc((size_t)BB * NBUK * 4);
    int* wmat = (int*)alloc((size_t)BB * NBUK * 4);
    int* bcnt = (int*)alloc(NBUK * 4);
    int* boff = (int*)alloc((NBUK + 1) * 4);

    k_init<<<256, 256, 0, stream>>>(pooled, stats, bcnt);
    k_f2bf<<<1024, 256, 0, stream>>>((const float4*)feat, (uint2*)zb);
    k_cnt<<<BB, 256, 0, stream>>>(dst, cmat, bcnt);
    k_bucket_scan<<<1, 256, 0, stream>>>(bcnt, boff);
    k_boffscan<<<NBUK, 256, 0, stream>>>(cmat, boff, wmat);
    k_bin2<<<BB, 256, 0, stream>>>(src, dst, wmat, binned);
    k_bucket_finish<<<NBUK, 256, 0, stream>>>(binned, boff, off, csr);

    for (int L = 0; L < 4; ++L) {
        float* s1 = stats + L * 256;
        float* s2 = s1 + 128;
        const float* s2p = (L > 0) ? (stats + (L - 1) * 256 + 128) : nullptr;
        const float* g2p = (L > 0) ? (bn2g + (L - 1) * 64) : nullptr;
        const float* b2p = (L > 0) ? (bn2b + (L - 1) * 64) : nullptr;
        k_agg<<<AGG_BLOCKS, 256, 0, stream>>>(zb, s2p, g2p, b2p, (L > 0) ? 1 : 0,
                                              csr, off, W1 + L * 4096, yb, s1,
                                              gid, pooled + (size_t)L * NG * 64);
        k_g2<<<AGG_BLOCKS, 256, 0, stream>>>(yb, s1, bn1g + L * 64, bn1b + L * 64,
                                             W2 + L * 4096, zb, s2);
    }
    k_pool4<<<AGG_BLOCKS, 256, 0, stream>>>(zb, stats + 3 * 256 + 128, bn2g + 3 * 64, bn2b + 3 * 64,
                                            gid, pooled + (size_t)4 * NG * 64);
    k_final<<<(NG * 16 + 255) / 256, 256, 0, stream>>>(pooled, pW, pb, out);
}